// Round 2
// baseline (196.118 us; speedup 1.0000x reference)
//
#include <hip/hip_runtime.h>
#include <hip/hip_cooperative_groups.h>

namespace cg = cooperative_groups;

// ContrastiveLoss on MI355X (gfx950), B=8192, D=128, labels in [0,2048).
// loss = -(1/cnt) sum_{i: P_i>0} [ S_i/P_i - M - ln Z_i ]
//   Z_i = sum_{j != i} exp(sim_ij - M),  sim = E E^T / T,  M = 1/T (valid shift).
//   S_i = (e_i . g_{lab_i} - e_i . e_i) / T  with fp32 class sums g_c.
//   P_i = count[lab_i] - 1.
// R13: single COOPERATIVE kernel fusing {prep-convert, class-sums, main,
//      finalize}. Main tile body is the verified R11 structure VERBATIM
//      (coalesced staging + XOR LDS layout, SQ_LDS_BANK_CONFLICT=0 measured,
//      16x16x32 MFMA). R12 post-mortem: pre-swizzled global_load_lds source
//      broke staging coalescing (64 scattered 16B lines/instr) and 64-col
//      chunks dropped MFMA-per-barrier 64->16 — reverted. Class-sums run
//      AFTER this block's main tiles (needs only raw inputs; gsum not needed
//      until fin phase) so they hide under the main-phase tail. Grid sized
//      from the occupancy query so cooperative launch can't over-subscribe;
//      every phase is grid-strided and correct for any G >= 1.
// Kept: plain __launch_bounds__(256) (R3/R7/R10: min-waves pinning forces
//      the VGPR/AGPR split-spill).

#define BATCH  8192
#define DIMK   128
#define INV_T  14.285714285714286f
#define MSUB   14.285714285714286f
#define K1     20.609929155311264f   // INV_T * log2(e)
#define K2     20.609929155311264f   // MSUB  * log2(e)
#define NTILES 1056                  // 528 macro-tiles x 2 row-halves

typedef short bf16x8 __attribute__((ext_vector_type(8)));
typedef float f32x4  __attribute__((ext_vector_type(4)));

__device__ __forceinline__ unsigned short f2bf_rne(float f) {
    unsigned u = __float_as_uint(f);
    u += 0x7FFFu + ((u >> 16) & 1u);
    return (unsigned short)(u >> 16);
}
__device__ __forceinline__ float bf2f(unsigned short b) {
    return __uint_as_float(((unsigned)b) << 16);
}

__global__ __launch_bounds__(256) void
contrastive_fused(const float* __restrict__ emb, const int* __restrict__ labels,
                  ushort* __restrict__ Ebf, float* __restrict__ gsum,
                  int* __restrict__ gcnt, float* __restrict__ zpartR,
                  float* __restrict__ zcol, float* __restrict__ bpart,
                  int* __restrict__ bcnt, int* __restrict__ ticket,
                  float* __restrict__ out) {
    // 36 KB shared, reused per phase:
    //   main:      Bs 32 KB (2048 16B units) + cpart 4 KB
    //   class-sum: labs 32 KB
    //   finalize:  sf/si/lastflag scalars
    __shared__ __align__(16) char smraw[36864];
    cg::grid_group grid = cg::this_grid();
    const int G    = gridDim.x;
    const int bx   = blockIdx.x;
    const int tid  = threadIdx.x;
    const int lane = tid & 63;
    const int wid  = tid >> 6;
    const int quad = lane >> 4;
    const int l16  = lane & 15;

    // ---------------- Phase 1: fp32->bf16 convert + zero Z partials --------
    if (bx == 0 && tid == 0) *ticket = 0;
    for (int i = bx * 256 + tid; i < 262144; i += G * 256) {
        if (i < 67584) {                       // zpartR (1 MB) + zcol (32 KB)
            float4 z = {0.f, 0.f, 0.f, 0.f};
            ((float4*)zpartR)[i] = z;
        }
        float4 v = ((const float4*)emb)[i];
        ushort4 o;
        o.x = f2bf_rne(v.x); o.y = f2bf_rne(v.y);
        o.z = f2bf_rne(v.z); o.w = f2bf_rne(v.w);
        ((ushort4*)Ebf)[i] = o;
    }
    grid.sync();

    // ---------------- Phase 2: Z partials over the upper triangle ----------
    // Verified R11 body. Block covers rows [ti*256 + half*128, +128) x
    // cols [tj*256, +256); 2 LDS phases of 128 cols; conflict-free XOR
    // layout: 16B unit for (col,c) at (col>>4)*256 + c*16 + ((col&15)^c).
    {
        ushort* Bs = (ushort*)smraw;                          // 2048 16B units
        float (*cpart)[256] = (float (*)[256])(smraw + 32768);

        for (int tt = bx; tt < NTILES; tt += G) {
            int b = tt >> 1;
            const int half = tt & 1;
            int ti = 0;
            while (b >= 32 - ti) { b -= 32 - ti; ++ti; }
            const int tj = ti + b;
            const int row_base = ti * 256 + half * 128 + wid * 32;

            bf16x8 afrag[2][4];
#pragma unroll
            for (int mt = 0; mt < 2; ++mt)
#pragma unroll
                for (int kk = 0; kk < 4; ++kk)
                    afrag[mt][kk] = *(const bf16x8*)(Ebf
                        + (size_t)(row_base + mt * 16 + l16) * DIMK
                        + kk * 32 + quad * 8);

            float zacc[8];
#pragma unroll
            for (int s = 0; s < 8; ++s) zacc[s] = 0.f;

#pragma unroll
            for (int phase = 0; phase < 2; ++phase) {
                const int col_base = tj * 256 + phase * 128;
                __syncthreads();   // Bs safe to overwrite
#pragma unroll
                for (int it = 0; it < 8; ++it) {
                    int f   = it * 256 + tid;
                    int col = f >> 4;
                    int c   = f & 15;
                    uint4 v = *(const uint4*)(Ebf
                        + (size_t)(col_base + col) * DIMK + c * 8);
                    *(uint4*)&Bs[((col >> 4) * 256 + c * 16 + ((col & 15) ^ c)) * 8] = v;
                }
                __syncthreads();

                for (int nt = 0; nt < 8; ++nt) {
                    bf16x8 bfrag[4];
#pragma unroll
                    for (int kk = 0; kk < 4; ++kk) {
                        const int c2 = kk * 4 + quad;
                        bfrag[kk] = *(const bf16x8*)&Bs[(nt * 256 + c2 * 16 + (l16 ^ c2)) * 8];
                    }

                    float csum = 0.f;
#pragma unroll
                    for (int mt = 0; mt < 2; ++mt) {
                        f32x4 c = {0.f, 0.f, 0.f, 0.f};
#pragma unroll
                        for (int kk = 0; kk < 4; ++kk)
                            c = __builtin_amdgcn_mfma_f32_16x16x32_bf16(
                                    afrag[mt][kk], bfrag[kk], c, 0, 0, 0);
#pragma unroll
                        for (int r = 0; r < 4; ++r) {
                            float e = __builtin_amdgcn_exp2f(__builtin_fmaf(c[r], K1, -K2));
                            zacc[mt * 4 + r] += e;
                            csum += e;
                        }
                    }
                    csum += __shfl_xor(csum, 16, 64);
                    csum += __shfl_xor(csum, 32, 64);
                    if (quad == 0) cpart[wid][phase * 128 + nt * 16 + l16] = csum;
                }
            }

            // Row partials: reduce each row-slot over the 16 lanes sharing it.
#pragma unroll
            for (int s = 0; s < 8; ++s) {
                float z = zacc[s];
#pragma unroll
                for (int m = 1; m <= 8; m <<= 1) z += __shfl_xor(z, m, 64);
                if (l16 == 0) {
                    int row = row_base + (s >> 2) * 16 + quad * 4 + (s & 3);
                    zpartR[(size_t)tj * BATCH + row] = z;
                }
            }

            // Col partials: combine 4 waves, one distributed atomic per column.
            __syncthreads();
            if (ti != tj) {
                float s = cpart[0][tid] + cpart[1][tid] + cpart[2][tid] + cpart[3][tid];
                atomicAdd(&zcol[tj * 256 + tid], s);
            }
        }
    }

    // ---------------- Phase 2b: class sums (hidden under main tail) --------
    // Reversed block index so the class blocks are disjoint from the blocks
    // carrying the 32 remainder tiles (low bx). Needs only raw emb/labels.
    {
        const int k = G - 1 - bx;
        if (k * 4 < 2048) {
            int* labs = (int*)smraw;
            __syncthreads();           // done with Bs/cpart
#pragma unroll
            for (int it = 0; it < 8; ++it)
                ((int4*)labs)[it * 256 + tid] = ((const int4*)labels)[it * 256 + tid];
            __syncthreads();

            for (int c = k * 4 + wid; c < 2048; c += G * 4) {
                float2 acc = {0.f, 0.f};
                int cnt = 0;
                int nl = labs[lane];
                for (int j0 = 0; j0 < BATCH; j0 += 64) {
                    int cur = nl;
                    int nidx = j0 + 64 < BATCH ? j0 + 64 : 0;
                    nl = labs[nidx + lane];
                    unsigned long long m = __ballot(cur == c);
                    cnt += __popcll(m);
                    while (m) {
                        int j = __ffsll(m) - 1;
                        m &= m - 1;
                        float2 v = *(const float2*)(emb + (size_t)(j0 + j) * DIMK + lane * 2);
                        acc.x += v.x; acc.y += v.y;
                    }
                }
                *(float2*)(gsum + (size_t)c * DIMK + lane * 2) = acc;
                if (lane == 0) gcnt[c] = cnt;
            }
        }
    }
    grid.sync();

    // ---------------- Phase 3: per-row finalize + ticket finale ------------
    {
        float* sf       = (float*)smraw;
        int*   si       = (int*)(smraw + 64);
        int*   lastflag = (int*)(smraw + 128);

        for (int u = bx; u < 512; u += G) {
            float wsum = 0.f;
            int   wcnt = 0;
#pragma unroll
            for (int it = 0; it < 4; ++it) {
                const int r   = u * 16 + wid * 4 + it;
                const int lab = labels[r];
                const int P   = gcnt[lab] - 1;

                float2 ev = *(const float2*)(emb  + (size_t)r   * DIMK + lane * 2);
                float2 gv = *(const float2*)(gsum + (size_t)lab * DIMK + lane * 2);
                unsigned bb = *(const unsigned*)(Ebf + (size_t)r * DIMK + lane * 2);
                float b0 = bf2f((unsigned short)(bb & 0xFFFF));
                float b1 = bf2f((unsigned short)(bb >> 16));

                float dotg = ev.x * gv.x + ev.y * gv.y;
                float ssd  = ev.x * ev.x + ev.y * ev.y;
                float sdbf = b0 * b0 + b1 * b1;
                float Z = 0.f;
                if (lane < 32)       Z = zpartR[(size_t)lane * BATCH + r];
                else if (lane == 32) Z = zcol[r];

#pragma unroll
                for (int m = 1; m <= 32; m <<= 1) {
                    dotg += __shfl_xor(dotg, m, 64);
                    ssd  += __shfl_xor(ssd,  m, 64);
                    sdbf += __shfl_xor(sdbf, m, 64);
                    Z    += __shfl_xor(Z,    m, 64);
                }
                Z -= __builtin_amdgcn_exp2f(__builtin_fmaf(sdbf, K1, -K2));  // remove diagonal

                const bool has = (P > 0);
                wsum += has ? ((dotg - ssd) * INV_T / (float)P - MSUB - __logf(Z)) : 0.f;
                wcnt += has ? 1 : 0;
            }

            if (lane == 0) { sf[wid] = wsum; si[wid] = wcnt; }
            __syncthreads();
            if (tid == 0) {
                bpart[u] = sf[0] + sf[1] + sf[2] + sf[3];
                bcnt [u] = si[0] + si[1] + si[2] + si[3];
            }
            __syncthreads();   // sf/si reusable next iteration
        }

        __threadfence();                               // release partials
        if (tid == 0)
            *lastflag = (atomicAdd(ticket, 1) == G - 1) ? 1 : 0;
        __syncthreads();
        if (*lastflag) {                               // block-uniform branch
            __threadfence();                           // acquire others' partials
            const int t = tid;
            float v = bpart[t] + bpart[t + 256];
            int   c = bcnt[t]  + bcnt[t + 256];
#pragma unroll
            for (int m = 1; m <= 32; m <<= 1) {
                v += __shfl_xor(v, m, 64);
                c += __shfl_xor(c, m, 64);
            }
            if ((t & 63) == 0) { sf[t >> 6] = v; si[t >> 6] = c; }
            __syncthreads();
            if (t == 0) {
                float tot = sf[0] + sf[1] + sf[2] + sf[3];
                int cc = si[0] + si[1] + si[2] + si[3];
                out[0] = -tot / (float)(cc > 0 ? cc : 1);
            }
        }
    }
}

extern "C" void kernel_launch(void* const* d_in, const int* in_sizes, int n_in,
                              void* d_out, int out_size, void* d_ws, size_t ws_size,
                              hipStream_t stream) {
    const float* emb  = (const float*)d_in[0];
    const int* labels = (const int*)d_in[1];
    float* out        = (float*)d_out;

    char* ws = (char*)d_ws;
    ushort* Ebf    = (ushort*)ws;                         // 2 MB  (8192*128*2)
    float*  zpartR = (float*)(ws + (2u << 20));           // 1 MB  (32*8192*4)
    float*  zcol   = (float*)(ws + (3u << 20));           // 32 KB (8192*4)
    float*  gsum   = (float*)(ws + (4u << 20));           // 1 MB  (2048*128*4)
    int*    gcnt   = (int*)  (ws + (5u << 20));           // 8 KB
    float*  bpart  = (float*)(ws + (5u << 20) + 8192);    // 8 KB
    int*    bcnt   = (int*)  (ws + (5u << 20) + 16384);   // 8 KB
    int*    ticket = (int*)  (ws + (5u << 20) + 24576);   // 4 B

    // Size the cooperative grid from the real occupancy (LDS 36 KB -> <=4
    // blocks/CU; VGPR may reduce it). All device phases are grid-strided,
    // so any G >= 1 is correct; G = occ*256 is the max co-resident grid.
    int occ = 0;
    if (hipOccupancyMaxActiveBlocksPerMultiprocessor(&occ, contrastive_fused, 256, 0)
            != hipSuccess || occ < 1)
        occ = 1;
    int G = occ * 256;
    if (G > NTILES) G = NTILES;

    void* args[] = { (void*)&emb, (void*)&labels, (void*)&Ebf, (void*)&gsum,
                     (void*)&gcnt, (void*)&zpartR, (void*)&zcol, (void*)&bpart,
                     (void*)&bcnt, (void*)&ticket, (void*)&out };
    hipLaunchCooperativeKernel((void*)contrastive_fused, dim3(G), dim3(256),
                               args, 0, stream);
}

// Round 3
// 110.228 us; speedup vs baseline: 1.7792x; 1.7792x over previous
//
#include <hip/hip_runtime.h>

// ContrastiveLoss on MI355X (gfx950), B=8192, D=128, labels in [0,2048).
// loss = -(1/cnt) sum_{i: P_i>0} [ S_i/P_i - M - ln Z_i ]
//   Z_i = sum_{j != i} exp(sim_ij - M),  sim = E E^T / T,  M = 1/T (valid shift).
//   S_i = (e_i . g_{lab_i} - e_i . e_i) / T  with fp32 class sums g_c.
//   P_i = count[lab_i] - 1.
// R14: revert to the verified R11 3-kernel structure (main body VERBATIM —
//      coalesced staging, XOR LDS layout w/ measured 0 bank conflicts,
//      16x16x32 MFMA, plain launch_bounds(256)). R13 post-mortem: cooperative
//      fusion halved co-resident parallelism (occ query -> G=512, 22% occ)
//      and added two cross-XCD grid.syncs; MfmaUtil 2% / VALU 6% / HBM 2%
//      confirmed the workload is latency-bound, so parallelism + few launches
//      is the whole game. Changes vs R11:
//      (a) finalize2 fused into finalize1 via device-scope ticket (one fewer
//          launch/graph node);
//      (b) zpartR pre-zeroing (1 MB) dropped — finalize masks the gather to
//          lane >= (r>>8), the only lanes ever written; only zcol (32 KB)
//          still zeroed, folded into the convert blocks.

#define BATCH 8192
#define DIMK  128
#define INV_T 14.285714285714286f
#define MSUB  14.285714285714286f
#define K1    20.609929155311264f   // INV_T * log2(e)
#define K2    20.609929155311264f   // MSUB  * log2(e)

typedef short bf16x8 __attribute__((ext_vector_type(8)));
typedef float f32x4  __attribute__((ext_vector_type(4)));

__device__ __forceinline__ unsigned short f2bf_rne(float f) {
    unsigned u = __float_as_uint(f);
    u += 0x7FFFu + ((u >> 16) & 1u);
    return (unsigned short)(u >> 16);
}
__device__ __forceinline__ float bf2f(unsigned short b) {
    return __uint_as_float(((unsigned)b) << 16);
}

// ---------------------------------------------------------------------------
// Prep: blocks [0,1024): fp32->bf16 cvt (4 elems/thread) + zero zcol (32 KB)
//       + reset the finale ticket.
//       blocks [1024,1536): class sums, 1 class per wave, labels staged in LDS.
__global__ __launch_bounds__(256) void
prep_kernel(const float* __restrict__ emb, const int* __restrict__ labels,
            ushort* __restrict__ Ebf, float* __restrict__ gsum, int* __restrict__ gcnt,
            float4* __restrict__ zcol4, int* __restrict__ ticket) {
    if (blockIdx.x < 1024) {
        int i = blockIdx.x * 256 + threadIdx.x;
        if (i == 0) *ticket = 0;
        if (i < 2048) {                       // zcol: 8192 floats = 2048 float4
            float4 z = {0.f, 0.f, 0.f, 0.f};
            zcol4[i] = z;
        }
        float4 v = ((const float4*)emb)[i];
        ushort4 o;
        o.x = f2bf_rne(v.x); o.y = f2bf_rne(v.y);
        o.z = f2bf_rne(v.z); o.w = f2bf_rne(v.w);
        ((ushort4*)Ebf)[i] = o;
    } else {
        __shared__ int labs[BATCH];           // 32 KB
        const int tid = threadIdx.x;
#pragma unroll
        for (int it = 0; it < 8; ++it)
            ((int4*)labs)[it * 256 + tid] = ((const int4*)labels)[it * 256 + tid];
        __syncthreads();

        const int lane = tid & 63;
        const int wid  = tid >> 6;
        const int c    = (blockIdx.x - 1024) * 4 + wid;   // class id [0,2048)
        float2 acc = {0.f, 0.f};
        int cnt = 0;
        int nl = labs[lane];
        for (int j0 = 0; j0 < BATCH; j0 += 64) {
            int cur = nl;
            int nidx = j0 + 64 < BATCH ? j0 + 64 : 0;
            nl = labs[nidx + lane];
            unsigned long long m = __ballot(cur == c);
            cnt += __popcll(m);
            while (m) {
                int j = __ffsll(m) - 1;
                m &= m - 1;
                float2 v = *(const float2*)(emb + (size_t)(j0 + j) * DIMK + lane * 2);
                acc.x += v.x; acc.y += v.y;
            }
        }
        *(float2*)(gsum + (size_t)c * DIMK + lane * 2) = acc;
        if (lane == 0) gcnt[c] = cnt;
    }
}

// ---------------------------------------------------------------------------
// Main: Z partials over the upper triangle. Grid 1056 = 528 macro-tiles x 2
// row-halves, block 256 (4 waves). Macro-tile (ti,tj), tj>=ti; this block
// covers rows [ti*256 + half*128, +128) x cols [tj*256, +256).
// Cols staged in two 128-col LDS phases, conflict-free XOR layout
// (measured: SQ_LDS_BANK_CONFLICT = 0):
//   chunk (col, c) -> 16B-unit (col>>4)*256 + c*16 + ((col&15)^c).
// Wave owns 32 rows (afrag[2][4]=32 VGPRs). PLAIN launch_bounds(256):
// min-waves pinning causes the VGPR/AGPR split-spill (R3/R7/R10).
// Row partials -> zpartR[tj][row] (plain stores). Col partials (off-diag
// only) -> cpart LDS combine -> atomicAdd zcol[col] (~16 adds/address).
__global__ __launch_bounds__(256) void
contrastive_main(const ushort* __restrict__ Ebf, float* __restrict__ zpartR,
                 float* __restrict__ zcol) {
    __shared__ __align__(16) ushort Bs[2048 * 8];     // 32 KB (2048 16B units)
    __shared__ float cpart[4][256];                   // 4 KB
    const int tid  = threadIdx.x;
    const int lane = tid & 63;
    const int wid  = tid >> 6;
    const int quad = lane >> 4;
    const int l16  = lane & 15;

    // block -> (ti, tj, half)
    int b = blockIdx.x >> 1;
    const int half = blockIdx.x & 1;
    int ti = 0;
    while (b >= 32 - ti) { b -= 32 - ti; ++ti; }
    const int tj = ti + b;
    const int row_base = ti * 256 + half * 128 + wid * 32;

    // A-fragments for this wave's 32 rows (register-resident), from global/L2.
    bf16x8 afrag[2][4];
#pragma unroll
    for (int mt = 0; mt < 2; ++mt)
#pragma unroll
        for (int kk = 0; kk < 4; ++kk)
            afrag[mt][kk] = *(const bf16x8*)(Ebf + (size_t)(row_base + mt * 16 + l16) * DIMK
                                             + kk * 32 + quad * 8);

    float zacc[8];
#pragma unroll
    for (int s = 0; s < 8; ++s) zacc[s] = 0.f;

#pragma unroll
    for (int phase = 0; phase < 2; ++phase) {
        const int col_base = tj * 256 + phase * 128;
        __syncthreads();   // Bs safe to overwrite (cheap no-op on phase 0)
        // Stage 128 cols: 2048 16B chunks; thread t handles chunk f = it*256+t:
        // col = f>>4, c = f&15; global read coalesced (16 lanes = 256B of one col);
        // LDS write at swizzled unit (col>>4)*256 + c*16 + ((col&15)^c) -> 2-way.
#pragma unroll
        for (int it = 0; it < 8; ++it) {
            int f   = it * 256 + tid;
            int col = f >> 4;
            int c   = f & 15;
            uint4 v = *(const uint4*)(Ebf + (size_t)(col_base + col) * DIMK + c * 8);
            *(uint4*)&Bs[((col >> 4) * 256 + c * 16 + ((col & 15) ^ c)) * 8] = v;
        }
        __syncthreads();

        for (int nt = 0; nt < 8; ++nt) {
            bf16x8 bfrag[4];
#pragma unroll
            for (int kk = 0; kk < 4; ++kk) {
                const int c2 = kk * 4 + quad;
                bfrag[kk] = *(const bf16x8*)&Bs[(nt * 256 + c2 * 16 + (l16 ^ c2)) * 8];
            }

            float csum = 0.f;
#pragma unroll
            for (int mt = 0; mt < 2; ++mt) {
                f32x4 c = {0.f, 0.f, 0.f, 0.f};
#pragma unroll
                for (int kk = 0; kk < 4; ++kk)
                    c = __builtin_amdgcn_mfma_f32_16x16x32_bf16(afrag[mt][kk], bfrag[kk], c, 0, 0, 0);
#pragma unroll
                for (int r = 0; r < 4; ++r) {
                    float e = __builtin_amdgcn_exp2f(__builtin_fmaf(c[r], K1, -K2));
                    zacc[mt * 4 + r] += e;
                    csum += e;
                }
            }
            // col partial for col (phase*128 + nt*16 + l16) over this wave's 32 rows
            csum += __shfl_xor(csum, 16, 64);
            csum += __shfl_xor(csum, 32, 64);
            if (quad == 0) cpart[wid][phase * 128 + nt * 16 + l16] = csum;
        }
    }

    // Row partials: reduce each row-slot over the 16 lanes sharing the row.
#pragma unroll
    for (int s = 0; s < 8; ++s) {
        float z = zacc[s];
#pragma unroll
        for (int m = 1; m <= 8; m <<= 1) z += __shfl_xor(z, m, 64);
        if (l16 == 0) {
            int row = row_base + (s >> 2) * 16 + quad * 4 + (s & 3);
            zpartR[(size_t)tj * BATCH + row] = z;
        }
    }

    // Col partials: combine the 4 waves, one distributed atomic per column.
    __syncthreads();
    if (ti != tj) {
        float s = cpart[0][tid] + cpart[1][tid] + cpart[2][tid] + cpart[3][tid];
        atomicAdd(&zcol[tj * 256 + tid], s);
    }
}

// ---------------------------------------------------------------------------
// Finalize: 512 blocks x 256 (4 waves); each wave processes 4 rows.
// Per row: lane l covers dims 2l,2l+1; lanes 0..31 read zpartR, lane 32 zcol.
// zpartR is only written for tj >= (r>>8): mask the gather (no pre-zeroing).
// Fused tail (R14): device-scope ticket; last block reduces the 512 partials.
__global__ __launch_bounds__(256) void
finalize1(const float* __restrict__ emb, const ushort* __restrict__ Ebf,
          const int* __restrict__ labels, const float* __restrict__ gsum,
          const int* __restrict__ gcnt, const float* __restrict__ zpartR,
          const float* __restrict__ zcol,
          float* __restrict__ bpart, int* __restrict__ bcnt,
          int* __restrict__ ticket, float* __restrict__ out) {
    __shared__ float sf[4];
    __shared__ int   si[4];
    __shared__ int   lastflag;
    const int lane = threadIdx.x & 63;
    const int wid  = threadIdx.x >> 6;

    float wsum = 0.f;
    int   wcnt = 0;
#pragma unroll
    for (int it = 0; it < 4; ++it) {
        const int r   = blockIdx.x * 16 + wid * 4 + it;
        const int lab = labels[r];
        const int P   = gcnt[lab] - 1;
        const int tp  = r >> 8;               // row's macro-tile

        float2 ev = *(const float2*)(emb  + (size_t)r   * DIMK + lane * 2);
        float2 gv = *(const float2*)(gsum + (size_t)lab * DIMK + lane * 2);
        unsigned bb = *(const unsigned*)(Ebf + (size_t)r * DIMK + lane * 2);
        float b0 = bf2f((unsigned short)(bb & 0xFFFF));
        float b1 = bf2f((unsigned short)(bb >> 16));

        float dotg = ev.x * gv.x + ev.y * gv.y;
        float ssd  = ev.x * ev.x + ev.y * ev.y;
        float sdbf = b0 * b0 + b1 * b1;
        float Z = 0.f;
        if (lane < 32) {
            if (lane >= tp) Z = zpartR[(size_t)lane * BATCH + r];
        } else if (lane == 32) {
            Z = zcol[r];
        }

#pragma unroll
        for (int m = 1; m <= 32; m <<= 1) {
            dotg += __shfl_xor(dotg, m, 64);
            ssd  += __shfl_xor(ssd,  m, 64);
            sdbf += __shfl_xor(sdbf, m, 64);
            Z    += __shfl_xor(Z,    m, 64);
        }
        Z -= __builtin_amdgcn_exp2f(__builtin_fmaf(sdbf, K1, -K2));  // remove diagonal

        const bool has = (P > 0);
        wsum += has ? ((dotg - ssd) * INV_T / (float)P - MSUB - __logf(Z)) : 0.f;
        wcnt += has ? 1 : 0;
    }

    if (lane == 0) { sf[wid] = wsum; si[wid] = wcnt; }
    __syncthreads();
    if (threadIdx.x == 0) {
        bpart[blockIdx.x] = sf[0] + sf[1] + sf[2] + sf[3];
        bcnt [blockIdx.x] = si[0] + si[1] + si[2] + si[3];
        __threadfence();                               // release partials
        lastflag = (atomicAdd(ticket, 1) == (int)gridDim.x - 1) ? 1 : 0;
    }
    __syncthreads();
    if (lastflag) {                                    // block-uniform branch
        __threadfence();                               // acquire others' partials
        const int t = threadIdx.x;
        float v = bpart[t] + bpart[t + 256];
        int   c = bcnt[t]  + bcnt[t + 256];
#pragma unroll
        for (int m = 1; m <= 32; m <<= 1) {
            v += __shfl_xor(v, m, 64);
            c += __shfl_xor(c, m, 64);
        }
        if ((t & 63) == 0) { sf[t >> 6] = v; si[t >> 6] = c; }
        __syncthreads();
        if (t == 0) {
            float tot = sf[0] + sf[1] + sf[2] + sf[3];
            int cc = si[0] + si[1] + si[2] + si[3];
            out[0] = -tot / (float)(cc > 0 ? cc : 1);
        }
    }
}

extern "C" void kernel_launch(void* const* d_in, const int* in_sizes, int n_in,
                              void* d_out, int out_size, void* d_ws, size_t ws_size,
                              hipStream_t stream) {
    const float* emb  = (const float*)d_in[0];
    const int* labels = (const int*)d_in[1];
    float* out        = (float*)d_out;

    char* ws = (char*)d_ws;
    ushort* Ebf    = (ushort*)ws;                         // 2 MB  (8192*128*2)
    float*  zpartR = (float*)(ws + (2u << 20));           // 1 MB  (32*8192*4)
    float*  zcol   = (float*)(ws + (3u << 20));           // 32 KB (8192*4)
    float*  gsum   = (float*)(ws + (4u << 20));           // 1 MB  (2048*128*4)
    int*    gcnt   = (int*)  (ws + (5u << 20));           // 8 KB
    float*  bpart  = (float*)(ws + (5u << 20) + 8192);    // 8 KB
    int*    bcnt   = (int*)  (ws + (5u << 20) + 16384);   // 8 KB
    int*    ticket = (int*)  (ws + (5u << 20) + 24576);   // 4 B

    prep_kernel<<<1536, 256, 0, stream>>>(emb, labels, Ebf, gsum, gcnt,
                                          (float4*)zcol, ticket);
    contrastive_main<<<1056, 256, 0, stream>>>(Ebf, zpartR, zcol);
    finalize1<<<512, 256, 0, stream>>>(emb, Ebf, labels, gsum, gcnt, zpartR, zcol,
                                       bpart, bcnt, ticket, out);
}